// Round 7
// baseline (843.288 us; speedup 1.0000x reference)
//
#include <hip/hip_runtime.h>
#include <hip/hip_bf16.h>

#define NN 50000
#define EE 100000
#define BB 2000
#define DIM 64
#define NF 14
#define EF 4
#define HID 128
#define EPAD 100096  // 391 * 256

typedef __attribute__((ext_vector_type(8))) _Float16 half8;   // 4 VGPRs
typedef __attribute__((ext_vector_type(4))) _Float16 half4;
typedef __attribute__((ext_vector_type(4))) float floatx4;    // MFMA C/D

// ---------------- fused weight prep: set2set transposes + GRU/NNConv fp16 + W2rT ----------------
__global__ void prep_weights_kernel(
    const float* __restrict__ lih, const float* __restrict__ lhh, const float* __restrict__ l1,
    const float* __restrict__ root, const float* __restrict__ b2,
    const float* __restrict__ wih, const float* __restrict__ whh,
    const float* __restrict__ bih, const float* __restrict__ bhh,
    const float* __restrict__ w2,
    float* __restrict__ lihT, float* __restrict__ lhhT, float* __restrict__ l1T,
    _Float16* __restrict__ W1h, _Float16* __restrict__ W2h, float* __restrict__ fbias,
    _Float16* __restrict__ W2rT) {
    int t = blockIdx.x * 256 + threadIdx.x;
    if (t < 64 * 8192) {
        int o = t >> 13, k = t & 8191, i = k >> 7, h = k & 127;
        W2rT[(size_t)o * 8192 + k] = (_Float16)w2[(size_t)(i * 64 + o) * 128 + h];
    }
    if (t < 256 * 128) { int j = t / 128, k = t % 128; lihT[k * 256 + j] = lih[t]; }
    if (t < 256 * 64) { int j = t / 64, k = t % 64; lhhT[k * 256 + j] = lhh[t]; }
    if (t < 64 * 128) { int d = t / 128, k = t % 128; l1T[k * 64 + d] = l1[t]; }
    if (t < 64 * 128) {
        int n = t >> 7, k = t & 127;
        W1h[t] = (_Float16)(k < 64 ? root[k * 64 + n] : b2[(size_t)(k - 64) * 64 + n]);
    }
    if (t < 256 * 128) {
        int n2 = t >> 7, k = t & 127;
        int g = n2 >> 6, j = n2 & 63;
        float v;
        if (g == 0)      v = (k < 64) ? wih[j * 64 + k]         : whh[j * 64 + (k - 64)];
        else if (g == 1) v = (k < 64) ? wih[(64 + j) * 64 + k]  : whh[(64 + j) * 64 + (k - 64)];
        else if (g == 2) v = (k < 64) ? wih[(128 + j) * 64 + k] : 0.f;
        else             v = (k < 64) ? 0.f                     : whh[(128 + j) * 64 + (k - 64)];
        W2h[t] = (_Float16)v;
    }
    if (t < 256) {
        int g = t >> 6, j = t & 63;
        float v = (g == 0) ? bih[j] + bhh[j]
                : (g == 1) ? bih[64 + j] + bhh[64 + j]
                : (g == 2) ? bih[128 + j] : bhh[128 + j];
        fbias[t] = v;
    }
}

// ---------------- fused: he16 (all EPAD*128) + lin0 (NN*64) + deg (EE) ----------------
__global__ void prep_ne_kernel(const float* __restrict__ ea, const float* __restrict__ w1,
                               const float* __restrict__ b1, _Float16* __restrict__ he,
                               const float* __restrict__ x, const float* __restrict__ l0w,
                               const float* __restrict__ l0b, float* __restrict__ hv,
                               const int* __restrict__ ei, float* __restrict__ deg) {
    int t = blockIdx.x * 256 + threadIdx.x;
    if (t < EPAD * 128) {
        int el = t >> 7, h = t & 127;
        float acc = 0.f;
        if (el < EE) {
            const float4 a = *(const float4*)(ea + (size_t)el * 4);
            const float4 w = *(const float4*)(w1 + h * 4);
            acc = fmaxf(b1[h] + a.x * w.x + a.y * w.y + a.z * w.z + a.w * w.w, 0.f);
        }
        he[t] = (_Float16)acc;
    }
    if (t < NN * 64) {
        int n = t >> 6, d = t & 63;
        float acc = l0b[d];
        #pragma unroll
        for (int f = 0; f < NF; f++) acc += x[n * NF + f] * l0w[d * NF + f];
        hv[t] = fmaxf(acc, 0.f);
    }
    if (t < EE) atomicAdd(&deg[ei[EE + t]], 1.0f);
}

// ---------------- msg GEMM: msg = G @ W2rT^T, G generated in-register ----------------
// Wave tile = 128 edges x 32 cols (was 64x64): halves per-wave B-fragment LDS reads (16->8),
// cutting the LDS-read redundancy that bounded round 5. Explicit load+ds_write double-buffer
// (round-5 staging, fastest measured). Fragment-order sB: conflict-free.
__global__ __launch_bounds__(256, 2) void msg_gemm_kernel(
    const float* __restrict__ hv, const _Float16* __restrict__ he16,
    const _Float16* __restrict__ W2rT, const int* __restrict__ ei,
    float* __restrict__ agg, float* __restrict__ xsum) {
    __shared__ _Float16 sB[2][16 * 64 * 8];   // [frag(cg*8+nt*4+ks)][lane][8]
    __shared__ _Float16 sXs[256 * 72];        // [edge][i], stride 72 (8B-aligned half4)
    __shared__ int sDst[256];
    const int t = threadIdx.x;
    const int eb = blockIdx.x * 256;
    const int lane = t & 63;
    const int w = t >> 6;
    const int col = lane & 15;
    const int quad = lane >> 4;
    const int eh = w >> 1;   // edge-half: 128 edges
    const int cg = w & 1;    // col-group: 32 cols

    if (t < 256) {
        int e = eb + t;
        sDst[t] = (e < EE) ? ei[EE + e] : 0;
    }
    #pragma unroll 4
    for (int rep = 0; rep < 16; rep++) {
        int idx = rep * 256 + t;
        int el = idx >> 4, d4 = idx & 15;
        int e = eb + el;
        float4 v = {0.f, 0.f, 0.f, 0.f};
        if (e < EE) {
            int src = ei[e];
            v = *(const float4*)(hv + (size_t)src * 64 + d4 * 4);
        }
        half4 h4 = {(_Float16)v.x, (_Float16)v.y, (_Float16)v.z, (_Float16)v.w};
        *(half4*)&sXs[el * 72 + d4 * 4] = h4;
    }

    // A fragments (i-invariant): 8 M-tiles of this wave's 128-edge half
    half8 heReg[8][4];
    #pragma unroll
    for (int mt = 0; mt < 8; mt++) {
        int row = eb + eh * 128 + mt * 16 + col;
        #pragma unroll
        for (int p = 0; p < 4; p++)
            heReg[mt][p] = *(const half8*)(he16 + (size_t)row * 128 + p * 32 + quad * 8);
    }

    floatx4 Cacc[8][2];
    #pragma unroll
    for (int mt = 0; mt < 8; mt++)
        #pragma unroll
        for (int nt = 0; nt < 2; nt++)
            Cacc[mt][nt] = (floatx4){0.f, 0.f, 0.f, 0.f};

    // staging: wave w stages frags f=w*4+rep  (f = cg'*8+nt'*4+ks': cg'=w>>1, nt'=w&1, ks'=rep)
    const _Float16* gsrc = W2rT + (size_t)((w >> 1) * 32 + (w & 1) * 16 + col) * 8192 + quad * 8;
    half8 pre[4];
    {
        #pragma unroll
        for (int rep = 0; rep < 4; rep++)
            pre[rep] = *(const half8*)(gsrc + rep * 32);
        #pragma unroll
        for (int rep = 0; rep < 4; rep++)
            *(half8*)&sB[0][((w * 4 + rep) * 64 + lane) * 8] = pre[rep];
    }
    __syncthreads();

    #pragma unroll 1
    for (int i4 = 0; i4 < 16; i4++) {
        half4 xsv[8];
        #pragma unroll
        for (int mt = 0; mt < 8; mt++)
            xsv[mt] = *(const half4*)&sXs[(eh * 128 + mt * 16 + col) * 72 + i4 * 4];
        #pragma unroll
        for (int ii = 0; ii < 4; ii++) {
            const int i = i4 * 4 + ii;
            const int buf = i & 1;
            if (i < 63) {
                #pragma unroll
                for (int rep = 0; rep < 4; rep++)
                    pre[rep] = *(const half8*)(gsrc + (size_t)(i + 1) * 128 + rep * 32);
            }
            #pragma unroll
            for (int ks = 0; ks < 4; ks++) {
                half8 bfr[2];
                #pragma unroll
                for (int nt = 0; nt < 2; nt++)
                    bfr[nt] = *(const half8*)&sB[buf][((cg * 8 + nt * 4 + ks) * 64 + lane) * 8];
                #pragma unroll
                for (int mt = 0; mt < 8; mt++) {
                    half8 afr = heReg[mt][ks] * xsv[mt][ii];
                    #pragma unroll
                    for (int nt = 0; nt < 2; nt++)
                        Cacc[mt][nt] = __builtin_amdgcn_mfma_f32_16x16x32_f16(afr, bfr[nt], Cacc[mt][nt], 0, 0, 0);
                }
            }
            if (i < 63) {
                #pragma unroll
                for (int rep = 0; rep < 4; rep++)
                    *(half8*)&sB[buf ^ 1][((w * 4 + rep) * 64 + lane) * 8] = pre[rep];
            }
            __syncthreads();
        }
    }

    // epilogue: scatter msg (C layout: row = quad*4+r within tile, col = col)
    #pragma unroll
    for (int mt = 0; mt < 8; mt++) {
        #pragma unroll
        for (int r = 0; r < 4; r++) {
            int el = eh * 128 + mt * 16 + quad * 4 + r;
            if (eb + el < EE) {
                float* ap = agg + (size_t)sDst[el] * 64 + cg * 32 + col;
                #pragma unroll
                for (int nt = 0; nt < 2; nt++)
                    atomicAdd(ap + nt * 16, Cacc[mt][nt][r]);
            }
        }
    }
    // xsum scatter (b2 term, applied in node_fused)
    #pragma unroll 4
    for (int rep = 0; rep < 64; rep++) {
        int idx = rep * 256 + t;
        int el = idx >> 6, d = idx & 63;
        if (eb + el < EE)
            atomicAdd(&xsum[(size_t)sDst[el] * 64 + d], (float)sXs[el * 72 + d]);
    }
}

// ---------------- fused node update: NNConv epilogue + GRU (MFMA) ----------------
__global__ __launch_bounds__(256, 2) void node_fused_kernel(
    const float* __restrict__ hv_in, float* __restrict__ agg,
    float* __restrict__ xsum, const float* __restrict__ deg,
    const _Float16* __restrict__ W1h, const _Float16* __restrict__ W2h,
    const float* __restrict__ fbias, const float* __restrict__ cb,
    float* __restrict__ hv_out) {
    __shared__ _Float16 sA1[64 * 136];  // [node][k]: k<64 hv, k>=64 xsum/deg
    __shared__ _Float16 sA2[64 * 136];  // [node][k]: k<64 m, k>=64 hv
    __shared__ float sH[64 * 68];       // h_old fp32, reused for h_new
    __shared__ float sAgg[64 * 68];     // agg/deg fp32
    const int t = threadIdx.x;
    const int nb = blockIdx.x * 64;
    const int n = t >> 2, part = t & 3;
    {
        int gn = nb + n;
        bool valid = gn < NN;
        float inv = 1.f;
        if (valid) inv = 1.f / fmaxf(deg[gn], 1.f);
        #pragma unroll
        for (int c4 = 0; c4 < 4; c4++) {
            int d0 = part * 16 + c4 * 4;
            float4 hvv = {0.f, 0.f, 0.f, 0.f}, agv = {0.f, 0.f, 0.f, 0.f}, xsv = {0.f, 0.f, 0.f, 0.f};
            if (valid) {
                hvv = *(const float4*)(hv_in + (size_t)gn * 64 + d0);
                agv = *(const float4*)(agg + (size_t)gn * 64 + d0);
                xsv = *(const float4*)(xsum + (size_t)gn * 64 + d0);
            }
            agv.x *= inv; agv.y *= inv; agv.z *= inv; agv.w *= inv;
            xsv.x *= inv; xsv.y *= inv; xsv.z *= inv; xsv.w *= inv;
            half4 hvh = {(_Float16)hvv.x, (_Float16)hvv.y, (_Float16)hvv.z, (_Float16)hvv.w};
            half4 xsh = {(_Float16)xsv.x, (_Float16)xsv.y, (_Float16)xsv.z, (_Float16)xsv.w};
            *(half4*)&sA1[n * 136 + d0] = hvh;
            *(half4*)&sA1[n * 136 + 64 + d0] = xsh;
            *(half4*)&sA2[n * 136 + 64 + d0] = hvh;
            *(float4*)&sH[n * 68 + d0] = hvv;
            *(float4*)&sAgg[n * 68 + d0] = agv;
        }
        if (valid) {
            float4 z = {0.f, 0.f, 0.f, 0.f};
            #pragma unroll
            for (int c4 = 0; c4 < 4; c4++) {
                int d0 = part * 16 + c4 * 4;
                *(float4*)(agg + (size_t)gn * 64 + d0) = z;
                *(float4*)(xsum + (size_t)gn * 64 + d0) = z;
            }
        }
    }
    __syncthreads();

    const int lane = t & 63, w = t >> 6;
    const int col = lane & 15, quad = lane >> 4;

    floatx4 C1[4];
    #pragma unroll
    for (int nt = 0; nt < 4; nt++) {
        float b = cb[nt * 16 + col];
        C1[nt] = (floatx4){b, b, b, b};
    }
    #pragma unroll
    for (int ks = 0; ks < 4; ks++) {
        half8 a = *(const half8*)&sA1[(w * 16 + col) * 136 + ks * 32 + quad * 8];
        #pragma unroll
        for (int nt = 0; nt < 4; nt++) {
            half8 bfr = *(const half8*)(W1h + (size_t)(nt * 16 + col) * 128 + ks * 32 + quad * 8);
            C1[nt] = __builtin_amdgcn_mfma_f32_16x16x32_f16(a, bfr, C1[nt], 0, 0, 0);
        }
    }
    #pragma unroll
    for (int nt = 0; nt < 4; nt++) {
        #pragma unroll
        for (int r = 0; r < 4; r++) {
            int node = w * 16 + quad * 4 + r;
            int j = nt * 16 + col;
            float m = fmaxf(C1[nt][r] + sAgg[node * 68 + j], 0.f);
            sA2[node * 136 + j] = (_Float16)m;
        }
    }
    __syncthreads();

    floatx4 C2[16];
    #pragma unroll
    for (int nt2 = 0; nt2 < 16; nt2++) {
        float b = fbias[nt2 * 16 + col];
        C2[nt2] = (floatx4){b, b, b, b};
    }
    #pragma unroll
    for (int ks = 0; ks < 4; ks++) {
        half8 a = *(const half8*)&sA2[(w * 16 + col) * 136 + ks * 32 + quad * 8];
        #pragma unroll
        for (int nt2 = 0; nt2 < 16; nt2++) {
            half8 bfr = *(const half8*)(W2h + (size_t)(nt2 * 16 + col) * 128 + ks * 32 + quad * 8);
            C2[nt2] = __builtin_amdgcn_mfma_f32_16x16x32_f16(a, bfr, C2[nt2], 0, 0, 0);
        }
    }
    float hnew[4][4];
    #pragma unroll
    for (int r = 0; r < 4; r++) {
        int node = w * 16 + quad * 4 + r;
        #pragma unroll
        for (int jt = 0; jt < 4; jt++) {
            int j = jt * 16 + col;
            float rr = 1.f / (1.f + expf(-C2[jt][r]));
            float zz = 1.f / (1.f + expf(-C2[4 + jt][r]));
            float ng = tanhf(C2[8 + jt][r] + rr * C2[12 + jt][r]);
            float hold = sH[node * 68 + j];
            hnew[r][jt] = (1.f - zz) * ng + zz * hold;
        }
    }
    __syncthreads();
    #pragma unroll
    for (int r = 0; r < 4; r++) {
        int node = w * 16 + quad * 4 + r;
        #pragma unroll
        for (int jt = 0; jt < 4; jt++)
            sH[node * 68 + jt * 16 + col] = hnew[r][jt];
    }
    __syncthreads();
    {
        int gn = nb + n;
        if (gn < NN) {
            #pragma unroll
            for (int c4 = 0; c4 < 4; c4++) {
                int d0 = part * 16 + c4 * 4;
                *(float4*)(hv_out + (size_t)gn * 64 + d0) = *(const float4*)&sH[n * 68 + d0];
            }
        }
    }
}

// ---------------- fused Set2Set (3 steps) + readout, one block per graph ----------------
__global__ __launch_bounds__(256) void set2set_kernel(
    const float* __restrict__ hv,
    const float* __restrict__ lihT, const float* __restrict__ lhhT,
    const float* __restrict__ l_bih, const float* __restrict__ l_bhh,
    const float* __restrict__ lin1T, const float* __restrict__ lin1_b,
    const float* __restrict__ lin2_w, const float* __restrict__ lin2_b,
    float* __restrict__ out) {
    __shared__ float outS[25 * 65];
    __shared__ float qs[128], qh[64], qc[64], gat[256], ew[32], aw[32], red[64];
    int g = blockIdx.x;
    int t = threadIdx.x;
    for (int p = t; p < 25 * 64; p += 256) {
        int j = p >> 6, i = p & 63;
        outS[j * 65 + i] = hv[(size_t)(g * 25 + j) * 64 + i];
    }
    if (t < 128) qs[t] = 0.f;
    if (t < 64) { qh[t] = 0.f; qc[t] = 0.f; }
    __syncthreads();
    for (int it = 0; it < 3; it++) {
        float acc = l_bih[t] + l_bhh[t];
        for (int k = 0; k < 128; k++) acc += qs[k] * lihT[k * 256 + t];
        for (int k = 0; k < 64; k++) acc += qh[k] * lhhT[k * 256 + t];
        gat[t] = acc;
        __syncthreads();
        if (t < 64) {
            float ig = 1.f / (1.f + expf(-gat[t]));
            float fg = 1.f / (1.f + expf(-gat[64 + t]));
            float gg = tanhf(gat[128 + t]);
            float og = 1.f / (1.f + expf(-gat[192 + t]));
            float c = fg * qc[t] + ig * gg;
            qc[t] = c;
            qh[t] = og * tanhf(c);
        }
        __syncthreads();
        if (t < 25) {
            float e = 0.f;
            for (int i = 0; i < 64; i++) e += outS[t * 65 + i] * qh[i];
            ew[t] = e;
        }
        __syncthreads();
        if (t == 0) {
            float mx = ew[0];
            for (int j = 1; j < 25; j++) mx = fmaxf(mx, ew[j]);
            float s = 0.f;
            for (int j = 0; j < 25; j++) { float a = expf(ew[j] - mx); aw[j] = a; s += a; }
            float inv = 1.f / s;
            for (int j = 0; j < 25; j++) aw[j] *= inv;
        }
        __syncthreads();
        if (t < 64) {
            float r = 0.f;
            for (int j = 0; j < 25; j++) r += aw[j] * outS[j * 65 + t];
            qs[t] = qh[t];
            qs[64 + t] = r;
        }
        __syncthreads();
    }
    if (t < 64) {
        float y1 = lin1_b[t];
        for (int k = 0; k < 128; k++) y1 += qs[k] * lin1T[k * 64 + t];
        y1 = fmaxf(y1, 0.f);
        red[t] = y1 * lin2_w[t];
    }
    __syncthreads();
    if (t == 0) {
        float y = lin2_b[0];
        for (int i = 0; i < 64; i++) y += red[i];
        out[g] = y;
    }
}

extern "C" void kernel_launch(void* const* d_in, const int* in_sizes, int n_in,
                              void* d_out, int out_size, void* d_ws, size_t ws_size,
                              hipStream_t stream) {
    const float* x        = (const float*)d_in[0];
    const float* ea       = (const float*)d_in[1];
    const int*   ei       = (const int*)  d_in[2];
    const float* lin0_w   = (const float*)d_in[4];
    const float* lin0_b   = (const float*)d_in[5];
    const float* mlp_w1   = (const float*)d_in[6];
    const float* mlp_b1   = (const float*)d_in[7];
    const float* mlp_w2   = (const float*)d_in[8];
    const float* mlp_b2   = (const float*)d_in[9];
    const float* root     = (const float*)d_in[10];
    const float* conv_b   = (const float*)d_in[11];
    const float* gru_wih  = (const float*)d_in[12];
    const float* gru_whh  = (const float*)d_in[13];
    const float* gru_bih  = (const float*)d_in[14];
    const float* gru_bhh  = (const float*)d_in[15];
    const float* lstm_wih = (const float*)d_in[16];
    const float* lstm_whh = (const float*)d_in[17];
    const float* lstm_bih = (const float*)d_in[18];
    const float* lstm_bhh = (const float*)d_in[19];
    const float* lin1_w   = (const float*)d_in[20];
    const float* lin1_b   = (const float*)d_in[21];
    const float* lin2_w   = (const float*)d_in[22];
    const float* lin2_b   = (const float*)d_in[23];
    float* out = (float*)d_out;

    // ---- workspace carve ----
    char* base = (char*)d_ws;
    size_t off = 0;
    auto carve = [&](size_t bytes) -> void* {
        void* r = base + off;
        off = (off + bytes + 255) & ~(size_t)255;
        return r;
    };
    float* hv   = (float*)carve((size_t)NN * 64 * 4);
    float* agg  = (float*)carve((size_t)NN * 64 * 4);   // agg+xsum+deg contiguous: one memset
    float* xsum = (float*)carve((size_t)NN * 64 * 4);
    float* deg  = (float*)carve((size_t)NN * 4);
    float* lihT = (float*)carve(128 * 256 * 4);
    float* lhhT = (float*)carve(64 * 256 * 4);
    float* l1T  = (float*)carve(128 * 64 * 4);
    float* fbias = (float*)carve(256 * 4);
    _Float16* he16 = (_Float16*)carve((size_t)EPAD * 128 * 2);
    _Float16* W2rT = (_Float16*)carve((size_t)64 * 8192 * 2);
    _Float16* W1h  = (_Float16*)carve((size_t)64 * 128 * 2);
    _Float16* W2h  = (_Float16*)carve((size_t)256 * 128 * 2);

    // ---- preamble (fused) ----
    hipMemsetAsync(agg, 0, (size_t)NN * 64 * 4 * 2 + (size_t)NN * 4, stream);  // agg+xsum+deg
    prep_weights_kernel<<<2048, 256, 0, stream>>>(lstm_wih, lstm_whh, lin1_w,
                                                  root, mlp_b2, gru_wih, gru_whh, gru_bih, gru_bhh,
                                                  mlp_w2, lihT, lhhT, l1T, W1h, W2h, fbias, W2rT);
    prep_ne_kernel<<<(EPAD * 128 + 255) / 256, 256, 0, stream>>>(ea, mlp_w1, mlp_b1, he16,
                                                                 x, lin0_w, lin0_b, hv, ei, deg);

    // ---- 3 message-passing + GRU iterations (node_fused re-zeros agg/xsum) ----
    for (int it = 0; it < 3; it++) {
        msg_gemm_kernel<<<EPAD / 256, 256, 0, stream>>>(hv, he16, W2rT, ei, agg, xsum);
        node_fused_kernel<<<(NN + 63) / 64, 256, 0, stream>>>(hv, agg, xsum, deg,
                                                              W1h, W2h, fbias, conv_b, hv);
    }

    // ---- Set2Set + readout ----
    set2set_kernel<<<BB, 256, 0, stream>>>(hv, lihT, lhhT, lstm_bih, lstm_bhh,
                                           l1T, lin1_b, lin2_w, lin2_b, out);
}

// Round 8
// 782.708 us; speedup vs baseline: 1.0774x; 1.0774x over previous
//
#include <hip/hip_runtime.h>
#include <hip/hip_bf16.h>

#define NN 50000
#define EE 100000
#define BB 2000
#define DIM 64
#define NF 14
#define EF 4
#define HID 128
#define EPAD 100096  // 391 * 256

typedef __attribute__((ext_vector_type(8))) _Float16 half8;   // 4 VGPRs
typedef __attribute__((ext_vector_type(4))) _Float16 half4;
typedef __attribute__((ext_vector_type(4))) float floatx4;    // MFMA C/D 16x16
typedef __attribute__((ext_vector_type(16))) float floatx16;  // MFMA C/D 32x32

// ---------------- fused weight prep: set2set transposes + GRU/NNConv fp16 + W2rT ----------------
__global__ void prep_weights_kernel(
    const float* __restrict__ lih, const float* __restrict__ lhh, const float* __restrict__ l1,
    const float* __restrict__ root, const float* __restrict__ b2,
    const float* __restrict__ wih, const float* __restrict__ whh,
    const float* __restrict__ bih, const float* __restrict__ bhh,
    const float* __restrict__ w2,
    float* __restrict__ lihT, float* __restrict__ lhhT, float* __restrict__ l1T,
    _Float16* __restrict__ W1h, _Float16* __restrict__ W2h, float* __restrict__ fbias,
    _Float16* __restrict__ W2rT) {
    int t = blockIdx.x * 256 + threadIdx.x;
    if (t < 64 * 8192) {
        int o = t >> 13, k = t & 8191, i = k >> 7, h = k & 127;
        W2rT[(size_t)o * 8192 + k] = (_Float16)w2[(size_t)(i * 64 + o) * 128 + h];
    }
    if (t < 256 * 128) { int j = t / 128, k = t % 128; lihT[k * 256 + j] = lih[t]; }
    if (t < 256 * 64) { int j = t / 64, k = t % 64; lhhT[k * 256 + j] = lhh[t]; }
    if (t < 64 * 128) { int d = t / 128, k = t % 128; l1T[k * 64 + d] = l1[t]; }
    if (t < 64 * 128) {
        int n = t >> 7, k = t & 127;
        W1h[t] = (_Float16)(k < 64 ? root[k * 64 + n] : b2[(size_t)(k - 64) * 64 + n]);
    }
    if (t < 256 * 128) {
        int n2 = t >> 7, k = t & 127;
        int g = n2 >> 6, j = n2 & 63;
        float v;
        if (g == 0)      v = (k < 64) ? wih[j * 64 + k]         : whh[j * 64 + (k - 64)];
        else if (g == 1) v = (k < 64) ? wih[(64 + j) * 64 + k]  : whh[(64 + j) * 64 + (k - 64)];
        else if (g == 2) v = (k < 64) ? wih[(128 + j) * 64 + k] : 0.f;
        else             v = (k < 64) ? 0.f                     : whh[(128 + j) * 64 + (k - 64)];
        W2h[t] = (_Float16)v;
    }
    if (t < 256) {
        int g = t >> 6, j = t & 63;
        float v = (g == 0) ? bih[j] + bhh[j]
                : (g == 1) ? bih[64 + j] + bhh[64 + j]
                : (g == 2) ? bih[128 + j] : bhh[128 + j];
        fbias[t] = v;
    }
}

// ---------------- fused: he16 (all EPAD*128) + lin0 (NN*64) + deg (EE) ----------------
__global__ void prep_ne_kernel(const float* __restrict__ ea, const float* __restrict__ w1,
                               const float* __restrict__ b1, _Float16* __restrict__ he,
                               const float* __restrict__ x, const float* __restrict__ l0w,
                               const float* __restrict__ l0b, float* __restrict__ hv,
                               const int* __restrict__ ei, float* __restrict__ deg) {
    int t = blockIdx.x * 256 + threadIdx.x;
    if (t < EPAD * 128) {
        int el = t >> 7, h = t & 127;
        float acc = 0.f;
        if (el < EE) {
            const float4 a = *(const float4*)(ea + (size_t)el * 4);
            const float4 w = *(const float4*)(w1 + h * 4);
            acc = fmaxf(b1[h] + a.x * w.x + a.y * w.y + a.z * w.z + a.w * w.w, 0.f);
        }
        he[t] = (_Float16)acc;
    }
    if (t < NN * 64) {
        int n = t >> 6, d = t & 63;
        float acc = l0b[d];
        #pragma unroll
        for (int f = 0; f < NF; f++) acc += x[n * NF + f] * l0w[d * NF + f];
        hv[t] = fmaxf(acc, 0.f);
    }
    if (t < EE) atomicAdd(&deg[ei[EE + t]], 1.0f);
}

// ---------------- msg GEMM: msg = G @ W2rT^T, G generated in-register ----------------
// Round-5 structure (wave = 64 edges x 64 cols, explicit load+ds_write dbuf, fragment-order
// sB, epilogue scatters) with MFMA shape 32x32x16: halves MFMA instr count (64->32 per
// wave per i) at identical B-bytes and afr VALU cost.
__global__ __launch_bounds__(256, 2) void msg_gemm_kernel(
    const float* __restrict__ hv, const _Float16* __restrict__ he16,
    const _Float16* __restrict__ W2rT, const int* __restrict__ ei,
    float* __restrict__ agg, float* __restrict__ xsum) {
    __shared__ _Float16 sB[2][16 * 64 * 8];   // [frag(ct*8+kc)][lane][8]
    __shared__ _Float16 sXs[256 * 72];        // [edge][i], stride 72 (8B-aligned half4)
    __shared__ int sDst[256];
    const int t = threadIdx.x;
    const int eb = blockIdx.x * 256;
    const int lane = t & 63;
    const int w = t >> 6;
    const int l32 = lane & 31;
    const int khalf = lane >> 5;   // k-half selector for 32x32x16 fragments

    if (t < 256) {
        int e = eb + t;
        sDst[t] = (e < EE) ? ei[EE + e] : 0;
    }
    #pragma unroll 4
    for (int rep = 0; rep < 16; rep++) {
        int idx = rep * 256 + t;
        int el = idx >> 4, d4 = idx & 15;
        int e = eb + el;
        float4 v = {0.f, 0.f, 0.f, 0.f};
        if (e < EE) {
            int src = ei[e];
            v = *(const float4*)(hv + (size_t)src * 64 + d4 * 4);
        }
        half4 h4 = {(_Float16)v.x, (_Float16)v.y, (_Float16)v.z, (_Float16)v.w};
        *(half4*)&sXs[el * 72 + d4 * 4] = h4;
    }

    // A fragments (i-invariant): 2 edge-tiles of 32, 8 k-chunks of 16
    // A layout 32x32x16: row = lane&31, k = khalf*8 + j
    half8 heReg[2][8];
    #pragma unroll
    for (int et = 0; et < 2; et++) {
        int row = eb + w * 64 + et * 32 + l32;
        #pragma unroll
        for (int kc = 0; kc < 8; kc++)
            heReg[et][kc] = *(const half8*)(he16 + (size_t)row * 128 + kc * 16 + khalf * 8);
    }

    floatx16 Cacc[2][2];
    #pragma unroll
    for (int et = 0; et < 2; et++)
        #pragma unroll
        for (int ct = 0; ct < 2; ct++)
            Cacc[et][ct] = (floatx16)(0.f);

    // staging: wave w stages frags f = w*4+rep (f = ct*8+kc); lane holds
    // B[n=l32][k=kc*16+khalf*8..+7] of col-tile ct -> global row (ct*32+l32)
    const _Float16* gsrcs[4];
    #pragma unroll
    for (int rep = 0; rep < 4; rep++) {
        int f = w * 4 + rep;
        int ct = f >> 3, kc = f & 7;
        gsrcs[rep] = W2rT + (size_t)(ct * 32 + l32) * 8192 + kc * 16 + khalf * 8;
    }
    half8 pre[4];
    {
        #pragma unroll
        for (int rep = 0; rep < 4; rep++)
            pre[rep] = *(const half8*)(gsrcs[rep]);
        #pragma unroll
        for (int rep = 0; rep < 4; rep++)
            *(half8*)&sB[0][((w * 4 + rep) * 64 + lane) * 8] = pre[rep];
    }
    __syncthreads();

    #pragma unroll 1
    for (int i4 = 0; i4 < 16; i4++) {
        half4 xsv[2];
        #pragma unroll
        for (int et = 0; et < 2; et++)
            xsv[et] = *(const half4*)&sXs[(w * 64 + et * 32 + l32) * 72 + i4 * 4];
        #pragma unroll
        for (int ii = 0; ii < 4; ii++) {
            const int i = i4 * 4 + ii;
            const int buf = i & 1;
            if (i < 63) {
                #pragma unroll
                for (int rep = 0; rep < 4; rep++)
                    pre[rep] = *(const half8*)(gsrcs[rep] + (size_t)(i + 1) * 128);
            }
            #pragma unroll
            for (int kc = 0; kc < 8; kc++) {
                half8 bfr[2];
                #pragma unroll
                for (int ct = 0; ct < 2; ct++)
                    bfr[ct] = *(const half8*)&sB[buf][((ct * 8 + kc) * 64 + lane) * 8];
                #pragma unroll
                for (int et = 0; et < 2; et++) {
                    half8 afr = heReg[et][kc] * xsv[et][ii];
                    #pragma unroll
                    for (int ct = 0; ct < 2; ct++)
                        Cacc[et][ct] = __builtin_amdgcn_mfma_f32_32x32x16_f16(afr, bfr[ct], Cacc[et][ct], 0, 0, 0);
                }
            }
            if (i < 63) {
                #pragma unroll
                for (int rep = 0; rep < 4; rep++)
                    *(half8*)&sB[buf ^ 1][((w * 4 + rep) * 64 + lane) * 8] = pre[rep];
            }
            __syncthreads();
        }
    }

    // epilogue: scatter msg. 32x32 C layout: col = lane&31, row = (reg&3)+8*(reg>>2)+4*khalf
    #pragma unroll
    for (int et = 0; et < 2; et++) {
        #pragma unroll
        for (int reg = 0; reg < 16; reg++) {
            int row = (reg & 3) + 8 * (reg >> 2) + 4 * khalf;
            int el = w * 64 + et * 32 + row;
            if (eb + el < EE) {
                float* ap = agg + (size_t)sDst[el] * 64 + l32;
                #pragma unroll
                for (int ct = 0; ct < 2; ct++)
                    atomicAdd(ap + ct * 32, Cacc[et][ct][reg]);
            }
        }
    }
    // xsum scatter (b2 term, applied in node_fused)
    #pragma unroll 4
    for (int rep = 0; rep < 64; rep++) {
        int idx = rep * 256 + t;
        int el = idx >> 6, d = idx & 63;
        if (eb + el < EE)
            atomicAdd(&xsum[(size_t)sDst[el] * 64 + d], (float)sXs[el * 72 + d]);
    }
}

// ---------------- fused node update: NNConv epilogue + GRU (MFMA) ----------------
__global__ __launch_bounds__(256, 2) void node_fused_kernel(
    const float* __restrict__ hv_in, float* __restrict__ agg,
    float* __restrict__ xsum, const float* __restrict__ deg,
    const _Float16* __restrict__ W1h, const _Float16* __restrict__ W2h,
    const float* __restrict__ fbias, const float* __restrict__ cb,
    float* __restrict__ hv_out) {
    __shared__ _Float16 sA1[64 * 136];  // [node][k]: k<64 hv, k>=64 xsum/deg
    __shared__ _Float16 sA2[64 * 136];  // [node][k]: k<64 m, k>=64 hv
    __shared__ float sH[64 * 68];       // h_old fp32, reused for h_new
    __shared__ float sAgg[64 * 68];     // agg/deg fp32
    const int t = threadIdx.x;
    const int nb = blockIdx.x * 64;
    const int n = t >> 2, part = t & 3;
    {
        int gn = nb + n;
        bool valid = gn < NN;
        float inv = 1.f;
        if (valid) inv = 1.f / fmaxf(deg[gn], 1.f);
        #pragma unroll
        for (int c4 = 0; c4 < 4; c4++) {
            int d0 = part * 16 + c4 * 4;
            float4 hvv = {0.f, 0.f, 0.f, 0.f}, agv = {0.f, 0.f, 0.f, 0.f}, xsv = {0.f, 0.f, 0.f, 0.f};
            if (valid) {
                hvv = *(const float4*)(hv_in + (size_t)gn * 64 + d0);
                agv = *(const float4*)(agg + (size_t)gn * 64 + d0);
                xsv = *(const float4*)(xsum + (size_t)gn * 64 + d0);
            }
            agv.x *= inv; agv.y *= inv; agv.z *= inv; agv.w *= inv;
            xsv.x *= inv; xsv.y *= inv; xsv.z *= inv; xsv.w *= inv;
            half4 hvh = {(_Float16)hvv.x, (_Float16)hvv.y, (_Float16)hvv.z, (_Float16)hvv.w};
            half4 xsh = {(_Float16)xsv.x, (_Float16)xsv.y, (_Float16)xsv.z, (_Float16)xsv.w};
            *(half4*)&sA1[n * 136 + d0] = hvh;
            *(half4*)&sA1[n * 136 + 64 + d0] = xsh;
            *(half4*)&sA2[n * 136 + 64 + d0] = hvh;
            *(float4*)&sH[n * 68 + d0] = hvv;
            *(float4*)&sAgg[n * 68 + d0] = agv;
        }
        if (valid) {
            float4 z = {0.f, 0.f, 0.f, 0.f};
            #pragma unroll
            for (int c4 = 0; c4 < 4; c4++) {
                int d0 = part * 16 + c4 * 4;
                *(float4*)(agg + (size_t)gn * 64 + d0) = z;
                *(float4*)(xsum + (size_t)gn * 64 + d0) = z;
            }
        }
    }
    __syncthreads();

    const int lane = t & 63, w = t >> 6;
    const int col = lane & 15, quad = lane >> 4;

    floatx4 C1[4];
    #pragma unroll
    for (int nt = 0; nt < 4; nt++) {
        float b = cb[nt * 16 + col];
        C1[nt] = (floatx4){b, b, b, b};
    }
    #pragma unroll
    for (int ks = 0; ks < 4; ks++) {
        half8 a = *(const half8*)&sA1[(w * 16 + col) * 136 + ks * 32 + quad * 8];
        #pragma unroll
        for (int nt = 0; nt < 4; nt++) {
            half8 bfr = *(const half8*)(W1h + (size_t)(nt * 16 + col) * 128 + ks * 32 + quad * 8);
            C1[nt] = __builtin_amdgcn_mfma_f32_16x16x32_f16(a, bfr, C1[nt], 0, 0, 0);
        }
    }
    #pragma unroll
    for (int nt = 0; nt < 4; nt++) {
        #pragma unroll
        for (int r = 0; r < 4; r++) {
            int node = w * 16 + quad * 4 + r;
            int j = nt * 16 + col;
            float m = fmaxf(C1[nt][r] + sAgg[node * 68 + j], 0.f);
            sA2[node * 136 + j] = (_Float16)m;
        }
    }
    __syncthreads();

    floatx4 C2[16];
    #pragma unroll
    for (int nt2 = 0; nt2 < 16; nt2++) {
        float b = fbias[nt2 * 16 + col];
        C2[nt2] = (floatx4){b, b, b, b};
    }
    #pragma unroll
    for (int ks = 0; ks < 4; ks++) {
        half8 a = *(const half8*)&sA2[(w * 16 + col) * 136 + ks * 32 + quad * 8];
        #pragma unroll
        for (int nt2 = 0; nt2 < 16; nt2++) {
            half8 bfr = *(const half8*)(W2h + (size_t)(nt2 * 16 + col) * 128 + ks * 32 + quad * 8);
            C2[nt2] = __builtin_amdgcn_mfma_f32_16x16x32_f16(a, bfr, C2[nt2], 0, 0, 0);
        }
    }
    float hnew[4][4];
    #pragma unroll
    for (int r = 0; r < 4; r++) {
        int node = w * 16 + quad * 4 + r;
        #pragma unroll
        for (int jt = 0; jt < 4; jt++) {
            int j = jt * 16 + col;
            float rr = 1.f / (1.f + expf(-C2[jt][r]));
            float zz = 1.f / (1.f + expf(-C2[4 + jt][r]));
            float ng = tanhf(C2[8 + jt][r] + rr * C2[12 + jt][r]);
            float hold = sH[node * 68 + j];
            hnew[r][jt] = (1.f - zz) * ng + zz * hold;
        }
    }
    __syncthreads();
    #pragma unroll
    for (int r = 0; r < 4; r++) {
        int node = w * 16 + quad * 4 + r;
        #pragma unroll
        for (int jt = 0; jt < 4; jt++)
            sH[node * 68 + jt * 16 + col] = hnew[r][jt];
    }
    __syncthreads();
    {
        int gn = nb + n;
        if (gn < NN) {
            #pragma unroll
            for (int c4 = 0; c4 < 4; c4++) {
                int d0 = part * 16 + c4 * 4;
                *(float4*)(hv_out + (size_t)gn * 64 + d0) = *(const float4*)&sH[n * 68 + d0];
            }
        }
    }
}

// ---------------- fused Set2Set (3 steps) + readout, one block per graph ----------------
__global__ __launch_bounds__(256) void set2set_kernel(
    const float* __restrict__ hv,
    const float* __restrict__ lihT, const float* __restrict__ lhhT,
    const float* __restrict__ l_bih, const float* __restrict__ l_bhh,
    const float* __restrict__ lin1T, const float* __restrict__ lin1_b,
    const float* __restrict__ lin2_w, const float* __restrict__ lin2_b,
    float* __restrict__ out) {
    __shared__ float outS[25 * 65];
    __shared__ float qs[128], qh[64], qc[64], gat[256], ew[32], aw[32], red[64];
    int g = blockIdx.x;
    int t = threadIdx.x;
    for (int p = t; p < 25 * 64; p += 256) {
        int j = p >> 6, i = p & 63;
        outS[j * 65 + i] = hv[(size_t)(g * 25 + j) * 64 + i];
    }
    if (t < 128) qs[t] = 0.f;
    if (t < 64) { qh[t] = 0.f; qc[t] = 0.f; }
    __syncthreads();
    for (int it = 0; it < 3; it++) {
        float acc = l_bih[t] + l_bhh[t];
        for (int k = 0; k < 128; k++) acc += qs[k] * lihT[k * 256 + t];
        for (int k = 0; k < 64; k++) acc += qh[k] * lhhT[k * 256 + t];
        gat[t] = acc;
        __syncthreads();
        if (t < 64) {
            float ig = 1.f / (1.f + expf(-gat[t]));
            float fg = 1.f / (1.f + expf(-gat[64 + t]));
            float gg = tanhf(gat[128 + t]);
            float og = 1.f / (1.f + expf(-gat[192 + t]));
            float c = fg * qc[t] + ig * gg;
            qc[t] = c;
            qh[t] = og * tanhf(c);
        }
        __syncthreads();
        if (t < 25) {
            float e = 0.f;
            for (int i = 0; i < 64; i++) e += outS[t * 65 + i] * qh[i];
            ew[t] = e;
        }
        __syncthreads();
        if (t == 0) {
            float mx = ew[0];
            for (int j = 1; j < 25; j++) mx = fmaxf(mx, ew[j]);
            float s = 0.f;
            for (int j = 0; j < 25; j++) { float a = expf(ew[j] - mx); aw[j] = a; s += a; }
            float inv = 1.f / s;
            for (int j = 0; j < 25; j++) aw[j] *= inv;
        }
        __syncthreads();
        if (t < 64) {
            float r = 0.f;
            for (int j = 0; j < 25; j++) r += aw[j] * outS[j * 65 + t];
            qs[t] = qh[t];
            qs[64 + t] = r;
        }
        __syncthreads();
    }
    if (t < 64) {
        float y1 = lin1_b[t];
        for (int k = 0; k < 128; k++) y1 += qs[k] * lin1T[k * 64 + t];
        y1 = fmaxf(y1, 0.f);
        red[t] = y1 * lin2_w[t];
    }
    __syncthreads();
    if (t == 0) {
        float y = lin2_b[0];
        for (int i = 0; i < 64; i++) y += red[i];
        out[g] = y;
    }
}

extern "C" void kernel_launch(void* const* d_in, const int* in_sizes, int n_in,
                              void* d_out, int out_size, void* d_ws, size_t ws_size,
                              hipStream_t stream) {
    const float* x        = (const float*)d_in[0];
    const float* ea       = (const float*)d_in[1];
    const int*   ei       = (const int*)  d_in[2];
    const float* lin0_w   = (const float*)d_in[4];
    const float* lin0_b   = (const float*)d_in[5];
    const float* mlp_w1   = (const float*)d_in[6];
    const float* mlp_b1   = (const float*)d_in[7];
    const float* mlp_w2   = (const float*)d_in[8];
    const float* mlp_b2   = (const float*)d_in[9];
    const float* root     = (const float*)d_in[10];
    const float* conv_b   = (const float*)d_in[11];
    const float* gru_wih  = (const float*)d_in[12];
    const float* gru_whh  = (const float*)d_in[13];
    const float* gru_bih  = (const float*)d_in[14];
    const float* gru_bhh  = (const float*)d_in[15];
    const float* lstm_wih = (const float*)d_in[16];
    const float* lstm_whh = (const float*)d_in[17];
    const float* lstm_bih = (const float*)d_in[18];
    const float* lstm_bhh = (const float*)d_in[19];
    const float* lin1_w   = (const float*)d_in[20];
    const float* lin1_b   = (const float*)d_in[21];
    const float* lin2_w   = (const float*)d_in[22];
    const float* lin2_b   = (const float*)d_in[23];
    float* out = (float*)d_out;

    // ---- workspace carve ----
    char* base = (char*)d_ws;
    size_t off = 0;
    auto carve = [&](size_t bytes) -> void* {
        void* r = base + off;
        off = (off + bytes + 255) & ~(size_t)255;
        return r;
    };
    float* hv   = (float*)carve((size_t)NN * 64 * 4);
    float* agg  = (float*)carve((size_t)NN * 64 * 4);   // agg+xsum+deg contiguous: one memset
    float* xsum = (float*)carve((size_t)NN * 64 * 4);
    float* deg  = (float*)carve((size_t)NN * 4);
    float* lihT = (float*)carve(128 * 256 * 4);
    float* lhhT = (float*)carve(64 * 256 * 4);
    float* l1T  = (float*)carve(128 * 64 * 4);
    float* fbias = (float*)carve(256 * 4);
    _Float16* he16 = (_Float16*)carve((size_t)EPAD * 128 * 2);
    _Float16* W2rT = (_Float16*)carve((size_t)64 * 8192 * 2);
    _Float16* W1h  = (_Float16*)carve((size_t)64 * 128 * 2);
    _Float16* W2h  = (_Float16*)carve((size_t)256 * 128 * 2);

    // ---- preamble (fused) ----
    hipMemsetAsync(agg, 0, (size_t)NN * 64 * 4 * 2 + (size_t)NN * 4, stream);  // agg+xsum+deg
    prep_weights_kernel<<<2048, 256, 0, stream>>>(lstm_wih, lstm_whh, lin1_w,
                                                  root, mlp_b2, gru_wih, gru_whh, gru_bih, gru_bhh,
                                                  mlp_w2, lihT, lhhT, l1T, W1h, W2h, fbias, W2rT);
    prep_ne_kernel<<<(EPAD * 128 + 255) / 256, 256, 0, stream>>>(ea, mlp_w1, mlp_b1, he16,
                                                                 x, lin0_w, lin0_b, hv, ei, deg);

    // ---- 3 message-passing + GRU iterations (node_fused re-zeros agg/xsum) ----
    for (int it = 0; it < 3; it++) {
        msg_gemm_kernel<<<EPAD / 256, 256, 0, stream>>>(hv, he16, W2rT, ei, agg, xsum);
        node_fused_kernel<<<(NN + 63) / 64, 256, 0, stream>>>(hv, agg, xsum, deg,
                                                              W1h, W2h, fbias, conv_b, hv);
    }

    // ---- Set2Set + readout ----
    set2set_kernel<<<BB, 256, 0, stream>>>(hv, lihT, lhhT, lstm_bih, lstm_bhh,
                                           l1T, lin1_b, lin2_w, lin2_b, out);
}